// Round 2
// 165.049 us; speedup vs baseline: 1.0119x; 1.0119x over previous
//
#include <hip/hip_runtime.h>
#include <math.h>

// Problem constants
#define VDIM   128
#define KCODES 512
#define NROWS  (32 * 4096)      // 131072
#define TILE_ROWS 128           // rows per block (4 waves x 32 rows)
#define TN 0.67882250993908565f // 0.06 * sqrt(128)

typedef __attribute__((ext_vector_type(8))) short bf16x8;  // MFMA A/B frag (4 VGPR)
typedef __attribute__((ext_vector_type(4))) float f32x4;   // MFMA C/D frag / 16B ld-st

__device__ __forceinline__ unsigned short f2bf(float f) {
    unsigned u = __float_as_uint(f);
    unsigned r = u + 0x7FFFu + ((u >> 16) & 1u);   // round-to-nearest-even
    return (unsigned short)(r >> 16);
}

__device__ __forceinline__ bf16x8 pack8(f32x4 a, f32x4 b) {
    bf16x8 v;
    v[0] = (short)f2bf(a[0]); v[1] = (short)f2bf(a[1]);
    v[2] = (short)f2bf(a[2]); v[3] = (short)f2bf(a[3]);
    v[4] = (short)f2bf(b[0]); v[5] = (short)f2bf(b[1]);
    v[6] = (short)f2bf(b[2]); v[7] = (short)f2bf(b[3]);
    return v;
}

// Normalize codes. embn: fp32 row-major (epilogue gather).
// ebf: bf16 in MFMA *fragment-linear* layout so vq_main lanes load B frags
// with stride-1 16B global loads (no LDS staging needed):
//   granule G = (k>>4)*256 + (d>>3)*16 + (k&15) holds dims [d&~7, +8) of code k
//   (identical per-lane bytes to the old LDS-staged layout).
__global__ void prep_emb(const float* __restrict__ emb0,
                         float* __restrict__ embn,
                         unsigned short* __restrict__ ebf) {
    int k = blockIdx.x;       // KCODES blocks
    int l = threadIdx.x;      // 64 threads = 1 wave
    const float* row = emb0 + (size_t)k * VDIM;
    float a = row[l];
    float b = row[l + 64];
    float ss = a * a + b * b;
    #pragma unroll
    for (int off = 32; off; off >>= 1) ss += __shfl_xor(ss, off);
    float nrm = sqrtf(ss);
    float ea = (TN * a) / nrm;
    float eb = (TN * b) / nrm;
    embn[(size_t)k * VDIM + l]      = ea;
    embn[(size_t)k * VDIM + l + 64] = eb;
    // fragment-linear bf16 table
    size_t base = ((size_t)(k >> 4) << 11) + ((size_t)(k & 15) << 3);
    int d1 = l;         // dim handled: l
    int d2 = l + 64;    // dim handled: l+64
    ebf[base + ((size_t)(d1 >> 3) << 7) + (d1 & 7)] = f2bf(ea);
    ebf[base + ((size_t)(d2 >> 3) << 7) + (d2 & 7)] = f2bf(eb);
}

// Main: 4 waves x 32 rows, NO barriers in the main loop. A frags resident in
// VGPRs; B frags read straight from the L2-resident fragment-linear table
// (64 lanes x 16B consecutive = perfectly coalesced, ~17 TB/s aggregate vs
// 34.5 TB/s L2 ceiling). LDS only stages per-row results for the epilogue.
// argmin(dist) == argmax(dot(x0,e)) since ||x|| = ||e|| = tn exactly.
__global__ __launch_bounds__(256, 4) void vq_main(
        const float* __restrict__ x0,
        const unsigned short* __restrict__ ebf,
        const float* __restrict__ embn,
        unsigned* __restrict__ hist,
        float* __restrict__ out0,
        float* __restrict__ out1,
        float* __restrict__ out2) {
    __shared__ int   sbesti[TILE_ROWS];
    __shared__ float sdot[TILE_ROWS];
    __shared__ float sn0[TILE_ROWS];

    int t = threadIdx.x;
    int w = t >> 6;           // wave 0..3
    int l = t & 63;
    int n15 = l & 15;         // MFMA m (A rows), n (B cols), col (C)
    int q = l >> 4;           // quad: input k = q*8 + j; C row = q*4 + r

    // ---- Load A: 2 strips x 16 rows, K=128 as 4 k-chunks; fp32 -> bf16 frags
    int rowbase = blockIdx.x * TILE_ROWS + (w << 5);
    bf16x8 afr[2][4];
    float nsq[2];
    #pragma unroll
    for (int s = 0; s < 2; ++s) {
        const float* xrow = x0 + (size_t)(rowbase + (s << 4) + n15) * VDIM + (q << 3);
        float p0 = 0.f, p1 = 0.f;
        #pragma unroll
        for (int kc = 0; kc < 4; ++kc) {
            const f32x4* xp = (const f32x4*)(xrow + (kc << 5));
            f32x4 a = xp[0], b = xp[1];
            p0 = fmaf(a[0], a[0], p0); p1 = fmaf(a[1], a[1], p1);
            p0 = fmaf(a[2], a[2], p0); p1 = fmaf(a[3], a[3], p1);
            p0 = fmaf(b[0], b[0], p0); p1 = fmaf(b[1], b[1], p1);
            p0 = fmaf(b[2], b[2], p0); p1 = fmaf(b[3], b[3], p1);
            afr[s][kc] = pack8(a, b);
        }
        nsq[s] = p0 + p1;
        nsq[s] += __shfl_xor(nsq[s], 16, 64);   // reduce ||x0||^2 across quads
        nsq[s] += __shfl_xor(nsq[s], 32, 64);
    }

    float best[2][4];
    int   bidx[2][4];
    #pragma unroll
    for (int s = 0; s < 2; ++s)
        #pragma unroll
        for (int r = 0; r < 4; ++r) { best[s][r] = -3.4e38f; bidx[s][r] = 0; }

    const f32x4 zero4 = {0.f, 0.f, 0.f, 0.f};
    const bf16x8* __restrict__ bt = (const bf16x8*)ebf;   // fragment-linear table

    // ---- 32 chunks of 16 codes, B frags direct from L2 (no LDS, no syncs)
    #pragma unroll 2
    for (int cn = 0; cn < 32; ++cn) {
        const bf16x8* bp = bt + (cn << 8) + l;
        bf16x8 b0 = bp[0], b1 = bp[64], b2 = bp[128], b3 = bp[192];
        int nbase = (cn << 4) + n15;
        #pragma unroll
        for (int s = 0; s < 2; ++s) {
            f32x4 acc = __builtin_amdgcn_mfma_f32_16x16x32_bf16(afr[s][0], b0, zero4, 0, 0, 0);
            acc = __builtin_amdgcn_mfma_f32_16x16x32_bf16(afr[s][1], b1, acc, 0, 0, 0);
            acc = __builtin_amdgcn_mfma_f32_16x16x32_bf16(afr[s][2], b2, acc, 0, 0, 0);
            acc = __builtin_amdgcn_mfma_f32_16x16x32_bf16(afr[s][3], b3, acc, 0, 0, 0);
            #pragma unroll
            for (int r = 0; r < 4; ++r) {
                float d = acc[r];
                if (d > best[s][r]) { best[s][r] = d; bidx[s][r] = nbase; }
            }
        }
    }

    // ---- Reduce argmax across the 16 lanes (C cols) holding the same row
    #pragma unroll
    for (int m = 1; m <= 8; m <<= 1) {
        #pragma unroll
        for (int s = 0; s < 2; ++s)
            #pragma unroll
            for (int r = 0; r < 4; ++r) {
                float ov = __shfl_xor(best[s][r], m, 64);
                int   oi = __shfl_xor(bidx[s][r], m, 64);
                if (ov > best[s][r] || (ov == best[s][r] && oi < bidx[s][r])) {
                    best[s][r] = ov; bidx[s][r] = oi;
                }
            }
    }

    // ---- Stage per-row results to LDS for the coalesced epilogue
    if (n15 == 0) {
        #pragma unroll
        for (int s = 0; s < 2; ++s)
            #pragma unroll
            for (int r = 0; r < 4; ++r) {
                int lr = (w << 5) + (s << 4) + (q << 2) + r;  // C row = q*4+r
                sbesti[lr] = bidx[s][r];
                sdot[lr]   = best[s][r];
            }
    }
    if (q == 0) {
        #pragma unroll
        for (int s = 0; s < 2; ++s) sn0[(w << 5) + (s << 4) + n15] = nsq[s];
    }
    __syncthreads();

    // ---- Epilogue A: coalesced out0 copy (32 lanes cover one row's 512 B)
    // Nontemporal: don't let the 64 MB output stream evict x0 from L3.
    size_t blockrow = (size_t)blockIdx.x * TILE_ROWS;
    #pragma unroll
    for (int pass = 0; pass < 16; ++pass) {
        int lr = (pass << 3) + (t >> 5);   // 8 rows per pass
        int v4 = t & 31;                   // float4 slot within the row
        int bi = sbesti[lr];
        f32x4 e = *((const f32x4*)(embn + (size_t)bi * VDIM) + v4);
        __builtin_nontemporal_store(e, (f32x4*)(out0 + (blockrow + lr) * (size_t)VDIM) + v4);
    }

    // ---- Epilogue B: per-row scalars (threads 0..127)
    if (t < TILE_ROWS) {
        size_t row = blockrow + t;
        int bi = sbesti[t];
        float dotv = sdot[t];
        float nn = sn0[t];
        float sc = TN / sqrtf(nn);                      // x = sc * x0
        float o1 = 2.f * TN * TN - 2.f * sc * dotv;     // ||x||^2=||e||^2=tn^2
        __builtin_nontemporal_store(o1, &out1[row]);
        float sm = sc - 1.f;
        __builtin_nontemporal_store(o1 + sm * sm * nn, &out2[row]);
        atomicAdd(&hist[bi], 1u);
    }
}

__global__ void entropy_k(const unsigned* __restrict__ hist,
                          float* __restrict__ out) {
    __shared__ float red[8];
    int t = threadIdx.x;   // KCODES threads
    float h = (float)hist[t];
    float p = h / (float)NROWS;
    float term = (h > 0.f) ? p * logf(p) : 0.f;
    #pragma unroll
    for (int off = 32; off; off >>= 1) term += __shfl_xor(term, off);
    if ((t & 63) == 0) red[t >> 6] = term;
    __syncthreads();
    if (t == 0) {
        float ssum = 0.f;
        #pragma unroll
        for (int i = 0; i < 8; i++) ssum += red[i];
        out[0] = -ssum;
    }
}

extern "C" void kernel_launch(void* const* d_in, const int* in_sizes, int n_in,
                              void* d_out, int out_size, void* d_ws, size_t ws_size,
                              hipStream_t stream) {
    const float* x0   = (const float*)d_in[0];
    const float* emb0 = (const float*)d_in[1];

    float* embn = (float*)d_ws;                              // 512*128 f32 = 256 KB
    unsigned* hist = (unsigned*)(embn + (size_t)KCODES * VDIM); // 512 u32
    unsigned short* ebf = (unsigned short*)(hist + KCODES);  // 512*128 bf16 = 128 KB

    float* out  = (float*)d_out;
    float* out0 = out;
    float* out1 = out0 + (size_t)NROWS * VDIM;
    float* out2 = out1 + NROWS;
    float* oent = out2 + NROWS;

    hipMemsetAsync(hist, 0, KCODES * sizeof(unsigned), stream);
    prep_emb<<<KCODES, 64, 0, stream>>>(emb0, embn, ebf);
    vq_main<<<NROWS / TILE_ROWS, 256, 0, stream>>>(x0, ebf, embn, hist,
                                                   out0, out1, out2);
    entropy_k<<<1, KCODES, 0, stream>>>(hist, oent);
}